// Round 3
// baseline (607.001 us; speedup 1.0000x reference)
//
#include <hip/hip_runtime.h>

#define N_NODES 20000
#define N_EDGES 200000
#define DIM 128
#define T_STEPS 8

typedef short short8 __attribute__((ext_vector_type(8)));
typedef float f32x4 __attribute__((ext_vector_type(4)));

static __device__ __forceinline__ unsigned short f2bf(float f) {
  union { float f; unsigned u; } v; v.f = f;
  unsigned r = v.u + 0x7fffu + ((v.u >> 16) & 1u);   // RNE
  return (unsigned short)(r >> 16);
}

// ---------------------------------------------------------------------------
// Repack the five 128x128 fp32 weight matrices (row-major W[k][n]) into bf16
// MFMA B-fragment order: pack[m][((nt*4+ks)*64+lane)*8+j] = bf16(W[k][n]) with
// n = nt*16 + (lane&15), k = ks*32 + (lane>>4)*8 + j.
// ---------------------------------------------------------------------------
__global__ void repack5(const float* __restrict__ w0,
                        const float* __restrict__ w1,
                        const float* __restrict__ w2,
                        const float* __restrict__ w3,
                        const float* __restrict__ w4,
                        unsigned short* __restrict__ pack) {
  int i = blockIdx.x * blockDim.x + threadIdx.x;
  if (i >= 5 * 16384) return;
  int m = i >> 14, r = i & 16383;
  int j = r & 7, lane = (r >> 3) & 63, ks = (r >> 9) & 3, nt = (r >> 11) & 7;
  int n = nt * 16 + (lane & 15);
  int k = ks * 32 + (lane >> 4) * 8 + j;
  const float* w = (m == 0) ? w0 : (m == 1) ? w1 : (m == 2) ? w2
                 : (m == 3) ? w3 : w4;
  pack[i] = f2bf(w[k * DIM + n]);
}

// ---------------------------------------------------------------------------
// Per-step masked scatter: agg[dst] += node_emb[src] * rel_emb[type] * w
// All fp32 (matches reference numerics modulo atomic order).
// One wave per edge (grid-stride). Wave-uniform time check; 2 dims per lane.
// ---------------------------------------------------------------------------
__global__ void scatter_step(const int* __restrict__ src,
                             const int* __restrict__ dst,
                             const int* __restrict__ etype,
                             const int* __restrict__ etime,
                             const float* __restrict__ ew,
                             const float* __restrict__ nemb,
                             const float* __restrict__ remb,
                             float* __restrict__ agg, int step) {
  int lane = threadIdx.x & 63;
  int wid = (blockIdx.x * blockDim.x + threadIdx.x) >> 6;
  int nw = (gridDim.x * blockDim.x) >> 6;
  for (int e = wid; e < N_EDGES; e += nw) {
    if (etime[e] != step) continue;          // wave-uniform branch
    int s = src[e], d = dst[e], rt = etype[e];
    float w = ew[e];
    float2 sv = *((const float2*)(nemb + s * DIM) + lane);
    float2 rv = *((const float2*)(remb + rt * DIM) + lane);
    float* ap = agg + d * DIM + lane * 2;
    atomicAdd(ap,     sv.x * rv.x * w);
    atomicAdd(ap + 1, sv.y * rv.y * w);
  }
}

// ---------------------------------------------------------------------------
// Fused per-step kernel: one wave per 16-row node tile.
//   H    = tanh(agg @ W_enc)                       (32 MFMAs)
//   zpre = H@Wz + S@Uz + bz ; cpre = H@Wh + S@Uh + bh   (128 MFMAs)
//   S'   = (1-sigmoid(zpre))*S + sigmoid(zpre)*tanh(cpre)
// MFMA 16x16x32_bf16 layouts (HW-verified): A: m=lane&15,k=quad*8+j;
// B: n=lane&15,k=quad*8+j;  C/D: n=lane&15, m=quad*4+reg.
// H goes C-layout -> A-layout via LDS (stride 136 => free 2-way bank alias).
// ---------------------------------------------------------------------------
__launch_bounds__(64)
__global__ void fused_step(const float* __restrict__ agg,
                           float* __restrict__ state,
                           const unsigned short* __restrict__ pack,
                           const float* __restrict__ bz,
                           const float* __restrict__ bh,
                           float* __restrict__ out,
                           int write_out) {
  __shared__ unsigned short hl[16 * 136];
  int lane = threadIdx.x;          // 0..63, one wave per block
  int row0 = blockIdx.x * 16;
  int q = lane >> 4, l15 = lane & 15;

  // ---- Phase A: H = tanh(agg @ W_enc) ----
  f32x4 acch[8];
#pragma unroll
  for (int nt = 0; nt < 8; nt++) acch[nt] = (f32x4){0.f, 0.f, 0.f, 0.f};
#pragma unroll
  for (int ks = 0; ks < 4; ks++) {
    const float* ap = agg + (row0 + l15) * DIM + ks * 32 + q * 8;
    float4 a0 = *(const float4*)ap;
    float4 a1 = *(const float4*)(ap + 4);
    short8 a;
    a[0] = (short)f2bf(a0.x); a[1] = (short)f2bf(a0.y);
    a[2] = (short)f2bf(a0.z); a[3] = (short)f2bf(a0.w);
    a[4] = (short)f2bf(a1.x); a[5] = (short)f2bf(a1.y);
    a[6] = (short)f2bf(a1.z); a[7] = (short)f2bf(a1.w);
#pragma unroll
    for (int nt = 0; nt < 8; nt++) {
      short8 b = *(const short8*)(pack + ((nt * 4 + ks) * 64 + lane) * 8);
      acch[nt] = __builtin_amdgcn_mfma_f32_16x16x32_bf16(a, b, acch[nt], 0, 0, 0);
    }
  }
  // tanh, write C-layout into LDS (bf16), re-read as A-frags
#pragma unroll
  for (int nt = 0; nt < 8; nt++)
#pragma unroll
    for (int r = 0; r < 4; r++)
      hl[(q * 4 + r) * 136 + nt * 16 + l15] = f2bf(tanhf(acch[nt][r]));
  __syncthreads();   // orders cross-lane LDS write->read

  short8 hA[4], sA[4];
#pragma unroll
  for (int ks = 0; ks < 4; ks++)
    hA[ks] = *(const short8*)&hl[l15 * 136 + ks * 32 + q * 8];
#pragma unroll
  for (int ks = 0; ks < 4; ks++) {
    const float* sp = state + (row0 + l15) * DIM + ks * 32 + q * 8;
    float4 s0 = *(const float4*)sp;
    float4 s1 = *(const float4*)(sp + 4);
    short8 s;
    s[0] = (short)f2bf(s0.x); s[1] = (short)f2bf(s0.y);
    s[2] = (short)f2bf(s0.z); s[3] = (short)f2bf(s0.w);
    s[4] = (short)f2bf(s1.x); s[5] = (short)f2bf(s1.y);
    s[6] = (short)f2bf(s1.z); s[7] = (short)f2bf(s1.w);
    sA[ks] = s;
  }

  // ---- Phase B: gate pre-activations ----
  f32x4 accz[8], accc[8];
#pragma unroll
  for (int nt = 0; nt < 8; nt++) {
    float vz = bz[nt * 16 + l15];
    float vh = bh[nt * 16 + l15];
    accz[nt] = (f32x4){vz, vz, vz, vz};
    accc[nt] = (f32x4){vh, vh, vh, vh};
  }
#pragma unroll
  for (int ks = 0; ks < 4; ks++) {
#pragma unroll
    for (int nt = 0; nt < 8; nt++) {
      int fo = ((nt * 4 + ks) * 64 + lane) * 8;
      short8 bwz = *(const short8*)(pack + 16384 * 1 + fo);
      short8 buz = *(const short8*)(pack + 16384 * 2 + fo);
      short8 bwh = *(const short8*)(pack + 16384 * 3 + fo);
      short8 buh = *(const short8*)(pack + 16384 * 4 + fo);
      accz[nt] = __builtin_amdgcn_mfma_f32_16x16x32_bf16(hA[ks], bwz, accz[nt], 0, 0, 0);
      accz[nt] = __builtin_amdgcn_mfma_f32_16x16x32_bf16(sA[ks], buz, accz[nt], 0, 0, 0);
      accc[nt] = __builtin_amdgcn_mfma_f32_16x16x32_bf16(hA[ks], bwh, accc[nt], 0, 0, 0);
      accc[nt] = __builtin_amdgcn_mfma_f32_16x16x32_bf16(sA[ks], buh, accc[nt], 0, 0, 0);
    }
  }

  // ---- Update (C-layout positions), fp32 state + fp32 output ----
#pragma unroll
  for (int nt = 0; nt < 8; nt++) {
#pragma unroll
    for (int r = 0; r < 4; r++) {
      int row = row0 + q * 4 + r;
      int col = nt * 16 + l15;
      float sold = state[row * DIM + col];
      float z = 1.f / (1.f + __expf(-accz[nt][r]));
      float c = tanhf(accc[nt][r]);
      float sn = (1.f - z) * sold + z * c;
      state[row * DIM + col] = sn;
      if (write_out) out[row * DIM + col] = sn;
    }
  }
}

extern "C" void kernel_launch(void* const* d_in, const int* in_sizes, int n_in,
                              void* d_out, int out_size, void* d_ws, size_t ws_size,
                              hipStream_t stream) {
  const int* eidx  = (const int*)d_in[0];
  const int* src   = eidx;
  const int* dst   = eidx + N_EDGES;
  const int* etype = (const int*)d_in[1];
  const int* etime = (const int*)d_in[2];
  const float* ew   = (const float*)d_in[3];
  const float* nemb = (const float*)d_in[4];
  const float* remb = (const float*)d_in[5];
  const float* Wenc = (const float*)d_in[6];
  const float* Wz   = (const float*)d_in[7];
  const float* Uz   = (const float*)d_in[8];
  const float* Wh   = (const float*)d_in[9];
  const float* Uh   = (const float*)d_in[10];
  const float* bz   = (const float*)d_in[11];
  const float* bh   = (const float*)d_in[12];
  // d_in[13] = num_times (constant 8 for this problem's fixed shapes)

  float* agg   = (float*)d_ws;                       // 20000*128 f32
  float* state = agg + N_NODES * DIM;                // 20000*128 f32
  unsigned short* pack = (unsigned short*)(state + N_NODES * DIM);  // 5*16384 bf16
  float* outp = (float*)d_out;

  hipMemsetAsync(state, 0, (size_t)N_NODES * DIM * sizeof(float), stream);
  repack5<<<(5 * 16384 + 255) / 256, 256, 0, stream>>>(Wenc, Wz, Uz, Wh, Uh, pack);

  for (int t = 0; t < T_STEPS; t++) {
    hipMemsetAsync(agg, 0, (size_t)N_NODES * DIM * sizeof(float), stream);
    scatter_step<<<1024, 256, 0, stream>>>(src, dst, etype, etime, ew, nemb, remb, agg, t);
    fused_step<<<N_NODES / 16, 64, 0, stream>>>(agg, state, pack, bz, bh, outp,
                                                (t == T_STEPS - 1) ? 1 : 0);
  }
}